// Round 6
// baseline (673.535 us; speedup 1.0000x reference)
//
#include <hip/hip_runtime.h>
#include <hip/hip_bf16.h>
#include <math.h>

// GAT layer on MI355X.
// R6: nontemporal out-stores in aggregate (keep xhb L3-resident);
// pre-cast x->bf16 so GEMM staging is pure int4 copies (BM=BN=128, 41KB LDS);
// bn_final: L3-hit out-read + nontemporal x-read/out-write.

#define N_NODES 100000
#define N_EDGES 1600000
#define NEG_SLOPE 0.2f
#define BN_EPS  1e-5f

typedef __attribute__((ext_vector_type(8))) short short8;
typedef __attribute__((ext_vector_type(4))) float f32x4;

// ---- workspace layout (bytes) ----
#define OFF_XHB     0            // [N,256] bf16 : 51,200,000
#define OFF_XB      51200000     // [N,256] bf16 : 51,200,000 (x cast)
#define OFF_ASRC    102400000    // [N,8] f32
#define OFF_ADST    105600000
#define OFF_ROWPTR  108800000
#define OFF_CURSOR  109200256
#define OFF_COUNTS  109600512
#define OFF_CSRSRC  110000768    // [E] i32
#define OFF_ACCUM   116400768    // [512] f32
#define OFF_BSUMS   116402816
#define OFF_BOFF    116403328
#define OFF_WT      116403968    // [256,256] bf16
#define OFF_PART    116535040    // [2048,512] f32
// total ~120.7 MB (R1-R3 used 116.4 MB OK; harness ws is larger)

__device__ __forceinline__ float leaky(float v) {
    return v > 0.f ? v : NEG_SLOPE * v;
}
__device__ __forceinline__ unsigned short f2bf(float f) {   // RNE
    unsigned int u = __float_as_uint(f);
    unsigned int r = (u + 0x7fffu + ((u >> 16) & 1u)) >> 16;
    return (unsigned short)r;
}
__device__ __forceinline__ float bf2f(unsigned short u) {
    return __uint_as_float(((unsigned int)u) << 16);
}

// ---------------- x -> bf16 (vectorized) ----------------------------------
__global__ __launch_bounds__(256) void cast_x(const float* __restrict__ x,
                                              unsigned short* __restrict__ xb) {
    const size_t t = (size_t)blockIdx.x * 256 + threadIdx.x;   // 3.2M threads
    const float4 a = *(const float4*)&x[t * 8];
    const float4 b = *(const float4*)&x[t * 8 + 4];
    ushort4 lo, hi;
    lo.x = f2bf(a.x); lo.y = f2bf(a.y); lo.z = f2bf(a.z); lo.w = f2bf(a.w);
    hi.x = f2bf(b.x); hi.y = f2bf(b.y); hi.z = f2bf(b.z); hi.w = f2bf(b.w);
    *(ushort4*)&xb[t * 8] = lo;
    *(ushort4*)&xb[t * 8 + 4] = hi;
}

// ---------------- W transpose+cast: Wt[n][k] = bf16(W[k][n]) --------------
__global__ __launch_bounds__(256) void castW(const float* __restrict__ W,
                                             unsigned short* __restrict__ Wt) {
    const int k = blockIdx.x;        // 256
    const int n = threadIdx.x;       // 256
    Wt[n * 256 + k] = f2bf(W[k * 256 + n]);
}

// ---------------- GEMM: xhb = bf16(xb @ W), MFMA 16x16x32 -----------------
// BM=128, BN=128, BK=32; 4 waves (2x2), wave tile 64x64. Pure int4 staging.
__global__ __launch_bounds__(256) void gemm_mfma(const unsigned short* __restrict__ xb,
                                                 const unsigned short* __restrict__ Wt,
                                                 unsigned short* __restrict__ xhb) {
    __shared__ unsigned short Asl[2][128 * 40];
    __shared__ unsigned short Bsl[2][128 * 40];
    const int tid = threadIdx.x;
    const int wid = tid >> 6, lane = tid & 63;
    const int wr = wid >> 1, wc = wid & 1;
    const int row0 = blockIdx.x * 128;
    const int col0 = blockIdx.y * 128;

    f32x4 acc[4][4];
#pragma unroll
    for (int m = 0; m < 4; ++m)
#pragma unroll
        for (int n = 0; n < 4; ++n) acc[m][n] = (f32x4){0.f, 0.f, 0.f, 0.f};

    int4 areg[2], breg[2];
    const int r_a[2] = {(tid + 0) >> 2, (tid + 256) >> 2};
    const int kq[2] = {(tid & 3) * 8, (tid & 3) * 8};

    // ---- prologue: tile 0 ----
#pragma unroll
    for (int q = 0; q < 2; ++q) {
        const int row = row0 + r_a[q];
        areg[q] = (row < N_NODES) ? *(const int4*)&xb[(size_t)row * 256 + kq[q]]
                                  : make_int4(0, 0, 0, 0);
        breg[q] = *(const int4*)&Wt[(size_t)(col0 + r_a[q]) * 256 + kq[q]];
    }
#pragma unroll
    for (int q = 0; q < 2; ++q) {
        *(int4*)&Asl[0][r_a[q] * 40 + kq[q]] = areg[q];
        *(int4*)&Bsl[0][r_a[q] * 40 + kq[q]] = breg[q];
    }
    __syncthreads();

    const int r16 = lane & 15;
    const int k8 = (lane >> 4) * 8;

    int buf = 0;
    for (int ks = 0; ks < 8; ++ks) {
        const bool more = ks < 7;
        if (more) {
            const int kk = (ks + 1) * 32;
#pragma unroll
            for (int q = 0; q < 2; ++q) {
                const int row = row0 + r_a[q];
                areg[q] = (row < N_NODES)
                              ? *(const int4*)&xb[(size_t)row * 256 + kk + kq[q]]
                              : make_int4(0, 0, 0, 0);
                breg[q] = *(const int4*)&Wt[(size_t)(col0 + r_a[q]) * 256 + kk + kq[q]];
            }
        }
        short8 afr[4], bfr[4];
#pragma unroll
        for (int m = 0; m < 4; ++m)
            afr[m] = *(const short8*)&Asl[buf][(wr * 64 + m * 16 + r16) * 40 + k8];
#pragma unroll
        for (int n = 0; n < 4; ++n)
            bfr[n] = *(const short8*)&Bsl[buf][(wc * 64 + n * 16 + r16) * 40 + k8];
#pragma unroll
        for (int m = 0; m < 4; ++m)
#pragma unroll
            for (int n = 0; n < 4; ++n)
                acc[m][n] = __builtin_amdgcn_mfma_f32_16x16x32_bf16(
                    afr[m], bfr[n], acc[m][n], 0, 0, 0);
        if (more) {
            const int nb = buf ^ 1;
#pragma unroll
            for (int q = 0; q < 2; ++q) {
                *(int4*)&Asl[nb][r_a[q] * 40 + kq[q]] = areg[q];
                *(int4*)&Bsl[nb][r_a[q] * 40 + kq[q]] = breg[q];
            }
            __syncthreads();
            buf = nb;
        }
    }

    // epilogue: C mapping col=lane&15, row=(lane>>4)*4+reg
#pragma unroll
    for (int m = 0; m < 4; ++m) {
        const int rbase = row0 + wr * 64 + m * 16 + (lane >> 4) * 4;
#pragma unroll
        for (int n = 0; n < 4; ++n) {
            const int col = col0 + wc * 64 + n * 16 + r16;
#pragma unroll
            for (int reg = 0; reg < 4; ++reg) {
                const int row = rbase + reg;
                if (row < N_NODES)
                    xhb[(size_t)row * 256 + col] = f2bf(acc[m][n][reg]);
            }
        }
    }
}

// ------------- a_src/a_dst from bf16 xh: one wave per node ----------------
__global__ __launch_bounds__(256) void att_vec(const unsigned short* __restrict__ xhb,
                                               const float* __restrict__ att_src,
                                               const float* __restrict__ att_dst,
                                               float* __restrict__ a_src,
                                               float* __restrict__ a_dst) {
    const int wid = (blockIdx.x * blockDim.x + threadIdx.x) >> 6;
    const int lane = threadIdx.x & 63;
    if (wid >= N_NODES) return;
    const ushort4 xv4 = *(const ushort4*)&xhb[(size_t)wid * 256 + lane * 4];
    const float x0 = bf2f(xv4.x), x1 = bf2f(xv4.y), x2 = bf2f(xv4.z), x3 = bf2f(xv4.w);
    const int h = lane >> 3;
    const int doff = (lane & 7) * 4;
    const float4 sv = *(const float4*)&att_src[h * 32 + doff];
    const float4 dv = *(const float4*)&att_dst[h * 32 + doff];
    float ss = x0 * sv.x + x1 * sv.y + x2 * sv.z + x3 * sv.w;
    float sd = x0 * dv.x + x1 * dv.y + x2 * dv.z + x3 * dv.w;
#pragma unroll
    for (int m = 1; m < 8; m <<= 1) {
        ss += __shfl_xor(ss, m);
        sd += __shfl_xor(sd, m);
    }
    if ((lane & 7) == 0) {
        a_src[wid * 8 + h] = ss;
        a_dst[wid * 8 + h] = sd;
    }
}

// ---------------- CSR build ----------------
__global__ void count_edges(const int* __restrict__ ei, int* __restrict__ counts) {
    const int e = blockIdx.x * blockDim.x + threadIdx.x;
    if (e < N_EDGES) atomicAdd(&counts[ei[N_EDGES + e]], 1);
}

__global__ __launch_bounds__(1024) void scan1(const int* __restrict__ counts,
                                              int* __restrict__ row_ptr,
                                              int* __restrict__ bsums) {
    __shared__ int s[1024];
    const int tid = threadIdx.x;
    const int idx = blockIdx.x * 1024 + tid;
    const int v = (idx < N_NODES) ? counts[idx] : 0;
    s[tid] = v;
    __syncthreads();
#pragma unroll
    for (int off = 1; off < 1024; off <<= 1) {
        const int add = (tid >= off) ? s[tid - off] : 0;
        __syncthreads();
        s[tid] += add;
        __syncthreads();
    }
    if (idx < N_NODES) row_ptr[idx] = s[tid] - v;
    if (tid == 1023) bsums[blockIdx.x] = s[1023];
}

__global__ __launch_bounds__(128) void scan2(const int* __restrict__ bsums,
                                             int* __restrict__ boff, int nb) {
    __shared__ int s[128];
    const int tid = threadIdx.x;
    const int v = (tid < nb) ? bsums[tid] : 0;
    s[tid] = v;
    __syncthreads();
#pragma unroll
    for (int off = 1; off < 128; off <<= 1) {
        const int add = (tid >= off) ? s[tid - off] : 0;
        __syncthreads();
        s[tid] += add;
        __syncthreads();
    }
    if (tid < nb) boff[tid] = s[tid] - v;
}

__global__ __launch_bounds__(1024) void scan3(int* __restrict__ row_ptr,
                                              int* __restrict__ cursor,
                                              const int* __restrict__ boff) {
    const int idx = blockIdx.x * 1024 + threadIdx.x;
    if (idx < N_NODES) {
        const int r = row_ptr[idx] + boff[blockIdx.x];
        row_ptr[idx] = r;
        cursor[idx] = r;
    }
    if (idx == 0) row_ptr[N_NODES] = N_EDGES;
}

__global__ void fill_csr(const int* __restrict__ ei, int* __restrict__ cursor,
                         int* __restrict__ csr_src) {
    const int e = blockIdx.x * blockDim.x + threadIdx.x;
    if (e < N_EDGES) {
        const int s = ei[e];
        const int d = ei[N_EDGES + e];
        const int pos = atomicAdd(&cursor[d], 1);
        csr_src[pos] = s;
    }
}

// ---------------- aggregate: one wave per node ----------------------------
// Nontemporal out-stores: don't evict xhb (51MB, L3-resident) with the
// 100MB output stream.
__global__ __launch_bounds__(256) void aggregate(const unsigned short* __restrict__ xhb,
                                                 const float* __restrict__ a_src,
                                                 const float* __restrict__ a_dst,
                                                 const int* __restrict__ row_ptr,
                                                 const int* __restrict__ csr_src,
                                                 const float* __restrict__ bias,
                                                 float* __restrict__ outbuf) {
    __shared__ int   j_cache[4][64];
    __shared__ float w_cache[4][64 * 8];
    const int wv = threadIdx.x >> 6;
    const int lane = threadIdx.x & 63;
    const int i = blockIdx.x * 4 + wv;        // grid exact: i < N_NODES
    const int beg = row_ptr[i], end = row_ptr[i + 1];
    const int deg = end - beg;
    const int deg64 = deg < 64 ? deg : 64;

    // ---- pass A ----
    const int h1 = lane & 7, sub = lane >> 3;
    const float ad1 = a_dst[i * 8 + h1];
    float sm_p = (sub == 0) ? __expf(leaky(a_src[i * 8 + h1] + ad1)) : 0.f;
    for (int t = sub; t < deg64; t += 8) {
        const int j = csr_src[beg + t];
        if (h1 == 0) j_cache[wv][t] = j;
        const float w = __expf(leaky(a_src[j * 8 + h1] + ad1));
        w_cache[wv][t * 8 + h1] = w;
        sm_p += w;
    }
#pragma unroll
    for (int m = 8; m < 64; m <<= 1) sm_p += __shfl_xor(sm_p, m);
    __syncthreads();

    // ---- pass B ----
    const int h2 = lane >> 3;
    float sm = __shfl(sm_p, h2);
    const float ad2 = a_dst[i * 8 + h2];
    const float as2 = a_src[i * 8 + h2];
    const float wself = __expf(leaky(as2 + ad2));
    const ushort4 sv4 = *(const ushort4*)&xhb[(size_t)i * 256 + lane * 4];
    float4 acc;
    acc.x = wself * bf2f(sv4.x); acc.y = wself * bf2f(sv4.y);
    acc.z = wself * bf2f(sv4.z); acc.w = wself * bf2f(sv4.w);

#pragma unroll 4
    for (int t = 0; t < deg64; ++t) {
        const int j = j_cache[wv][t];
        const float w = w_cache[wv][t * 8 + h2];
        const ushort4 v4 = *(const ushort4*)&xhb[(size_t)j * 256 + lane * 4];
        acc.x = fmaf(w, bf2f(v4.x), acc.x);
        acc.y = fmaf(w, bf2f(v4.y), acc.y);
        acc.z = fmaf(w, bf2f(v4.z), acc.z);
        acc.w = fmaf(w, bf2f(v4.w), acc.w);
    }
    for (int t = 64; t < deg; ++t) {          // rare tail (deg>64)
        const int j = csr_src[beg + t];
        const float w = __expf(leaky(a_src[j * 8 + h2] + ad2));
        sm += w;
        const ushort4 v4 = *(const ushort4*)&xhb[(size_t)j * 256 + lane * 4];
        acc.x = fmaf(w, bf2f(v4.x), acc.x);
        acc.y = fmaf(w, bf2f(v4.y), acc.y);
        acc.z = fmaf(w, bf2f(v4.z), acc.z);
        acc.w = fmaf(w, bf2f(v4.w), acc.w);
    }
    const float inv = 1.0f / sm;
    const float4 bv = *(const float4*)&bias[lane * 4];
    f32x4 res;
    res[0] = acc.x * inv + bv.x;
    res[1] = acc.y * inv + bv.y;
    res[2] = acc.z * inv + bv.z;
    res[3] = acc.w * inv + bv.w;
    __builtin_nontemporal_store(res, (f32x4*)&outbuf[(size_t)i * 256 + lane * 4]);
}

// ---------------- BatchNorm stats: two-stage ------------------------------
// Normal (allocating) reads: pulls `out` into L3 so bn_final's re-read hits.
__global__ __launch_bounds__(256) void bn_stats1(const float* __restrict__ outbuf,
                                                 float* __restrict__ part) {
    const int c = threadIdx.x;
    float s = 0.f, s2 = 0.f;
    for (int r = blockIdx.x; r < N_NODES; r += 2048) {
        const float v = outbuf[(size_t)r * 256 + c];
        s += v; s2 += v * v;
    }
    part[(size_t)blockIdx.x * 512 + c] = s;
    part[(size_t)blockIdx.x * 512 + 256 + c] = s2;
}

__global__ __launch_bounds__(512) void bn_stats2(const float* __restrict__ part,
                                                 float* __restrict__ accum) {
    const int c = threadIdx.x;
    float s = 0.f;
    for (int b = blockIdx.x; b < 2048; b += 64)
        s += part[(size_t)b * 512 + c];
    atomicAdd(&accum[c], s);
}

// ---------------- BN normalize + residual ---------------------------------
__global__ __launch_bounds__(256) void bn_final(float* __restrict__ out,
                                                const float* __restrict__ x,
                                                const float* __restrict__ accum,
                                                const float* __restrict__ gamma,
                                                const float* __restrict__ beta) {
    const size_t total4 = (size_t)N_NODES * 64;
    const size_t stride = (size_t)gridDim.x * blockDim.x;
    const float invN = 1.0f / (float)N_NODES;
    for (size_t f = blockIdx.x * blockDim.x + threadIdx.x; f < total4; f += stride) {
        const int c4 = ((int)(f & 63)) * 4;
        float4 v = *(float4*)&out[f * 4];                     // L3 hit (bn_stats1 allocated)
        const f32x4 xv = __builtin_nontemporal_load((const f32x4*)&x[f * 4]);
        const float4 sv = *(const float4*)&accum[c4];
        const float4 qv = *(const float4*)&accum[256 + c4];
        const float4 gv = *(const float4*)&gamma[c4];
        const float4 bv = *(const float4*)&beta[c4];
        f32x4 r;
        float mean, var;
        mean = sv.x * invN; var = qv.x * invN - mean * mean;
        r[0] = (v.x - mean) * rsqrtf(var + BN_EPS) * gv.x + bv.x + xv[0];
        mean = sv.y * invN; var = qv.y * invN - mean * mean;
        r[1] = (v.y - mean) * rsqrtf(var + BN_EPS) * gv.y + bv.y + xv[1];
        mean = sv.z * invN; var = qv.z * invN - mean * mean;
        r[2] = (v.z - mean) * rsqrtf(var + BN_EPS) * gv.z + bv.z + xv[2];
        mean = sv.w * invN; var = qv.w * invN - mean * mean;
        r[3] = (v.w - mean) * rsqrtf(var + BN_EPS) * gv.w + bv.w + xv[3];
        __builtin_nontemporal_store(r, (f32x4*)&out[f * 4]);
    }
}

extern "C" void kernel_launch(void* const* d_in, const int* in_sizes, int n_in,
                              void* d_out, int out_size, void* d_ws, size_t ws_size,
                              hipStream_t stream) {
    const float* x       = (const float*)d_in[0];
    const int*   ei      = (const int*)d_in[1];
    const float* W       = (const float*)d_in[2];
    const float* att_src = (const float*)d_in[3];
    const float* att_dst = (const float*)d_in[4];
    const float* bias    = (const float*)d_in[5];
    const float* gamma   = (const float*)d_in[6];
    const float* beta    = (const float*)d_in[7];
    float* out = (float*)d_out;

    char* ws = (char*)d_ws;
    unsigned short* xhb = (unsigned short*)(ws + OFF_XHB);
    unsigned short* xb  = (unsigned short*)(ws + OFF_XB);
    float* a_src   = (float*)(ws + OFF_ASRC);
    float* a_dst   = (float*)(ws + OFF_ADST);
    int*   row_ptr = (int*)(ws + OFF_ROWPTR);
    int*   cursor  = (int*)(ws + OFF_CURSOR);
    int*   counts  = (int*)(ws + OFF_COUNTS);
    int*   csr_src = (int*)(ws + OFF_CSRSRC);
    float* accum   = (float*)(ws + OFF_ACCUM);
    int*   bsums   = (int*)(ws + OFF_BSUMS);
    int*   boff    = (int*)(ws + OFF_BOFF);
    unsigned short* Wt = (unsigned short*)(ws + OFF_WT);
    float* part    = (float*)(ws + OFF_PART);

    hipMemsetAsync(counts, 0, N_NODES * sizeof(int), stream);
    hipMemsetAsync(accum, 0, 512 * sizeof(float), stream);

    cast_x<<<12500, 256, 0, stream>>>(x, xb);
    castW<<<256, 256, 0, stream>>>(W, Wt);
    gemm_mfma<<<dim3((N_NODES + 127) / 128, 2), 256, 0, stream>>>(xb, Wt, xhb);

    att_vec<<<(N_NODES * 64 + 255) / 256, 256, 0, stream>>>(xhb, att_src, att_dst,
                                                            a_src, a_dst);

    const int nsb = (N_NODES + 1023) / 1024;   // 98
    count_edges<<<(N_EDGES + 255) / 256, 256, 0, stream>>>(ei, counts);
    scan1<<<nsb, 1024, 0, stream>>>(counts, row_ptr, bsums);
    scan2<<<1, 128, 0, stream>>>(bsums, boff, nsb);
    scan3<<<nsb, 1024, 0, stream>>>(row_ptr, cursor, boff);
    fill_csr<<<(N_EDGES + 255) / 256, 256, 0, stream>>>(ei, cursor, csr_src);

    aggregate<<<N_NODES / 4, 256, 0, stream>>>(
        xhb, a_src, a_dst, row_ptr, csr_src, bias, out);

    bn_stats1<<<2048, 256, 0, stream>>>(out, part);
    bn_stats2<<<64, 512, 0, stream>>>(part, accum);
    bn_final<<<2048, 256, 0, stream>>>(out, x, accum, gamma, beta);
}